// Round 11
// baseline (162.516 us; speedup 1.0000x reference)
//
#include <hip/hip_runtime.h>
#include <hip/hip_bf16.h>
#include <math.h>

#define NB 4
#define NL 256
#define ND 512
#define NH 8
#define NR 64
#define NDK 64

typedef float f32x4 __attribute__((ext_vector_type(4)));
typedef short s16x8 __attribute__((ext_vector_type(8)));
typedef unsigned short u16;
typedef u16 u16x4 __attribute__((ext_vector_type(4)));
typedef u16 u16x8 __attribute__((ext_vector_type(8)));
typedef unsigned int u32;

static __device__ __forceinline__ u16 f2bf(float f) {
    __hip_bfloat16 h = __float2bfloat16(f);   // RNE
    return __builtin_bit_cast(unsigned short, h);
}
static __device__ __forceinline__ float bf2f(u16 u) {
    return __builtin_bit_cast(float, (u32)u << 16);
}

// ---------------------------------------------------------------------------
// Kernel A: convert inputs + weights f32 -> bf16.   (round-10 exact)
// jobs: 0 query, 1 key, 2 value (524288 ea); 3 Wq, 4 Wk, 5 Wv, 6 Wo (262144).
// ---------------------------------------------------------------------------
__global__ __launch_bounds__(256)
void convert_bf16_kernel(const float* __restrict__ q, const float* __restrict__ k,
                         const float* __restrict__ v, const float* __restrict__ wq,
                         const float* __restrict__ wk, const float* __restrict__ wv,
                         const float* __restrict__ wo,
                         u16* __restrict__ oq, u16* __restrict__ ok, u16* __restrict__ ov,
                         u16* __restrict__ owq, u16* __restrict__ owk,
                         u16* __restrict__ owv, u16* __restrict__ owo)
{
    const int job = blockIdx.y;
    const float* src; u16* dst; int n;
    switch (job) {
        case 0: src = q;  dst = oq;  n = 524288; break;
        case 1: src = k;  dst = ok;  n = 524288; break;
        case 2: src = v;  dst = ov;  n = 524288; break;
        case 3: src = wq; dst = owq; n = 262144; break;
        case 4: src = wk; dst = owk; n = 262144; break;
        case 5: src = wv; dst = owv; n = 262144; break;
        default: src = wo; dst = owo; n = 262144; break;
    }
    int idx = (blockIdx.x * 256 + threadIdx.x) * 4;
    if (idx >= n) return;
    f32x4 x = *(const f32x4*)&src[idx];
    u16x4 o;
    o.x = f2bf(x.x); o.y = f2bf(x.y); o.z = f2bf(x.z); o.w = f2bf(x.w);
    *(u16x4*)&dst[idx] = o;
}

// ---------------------------------------------------------------------------
// Kernel B: W-prep (f32 compute, bf16 out).   (round-10 exact)
//  z=0: W3[h*64+r][e] = sum_d rel_k[h,r,d] * Wq[h*64+d][e]   (for c2p)
//  z=1: W2[h*64+r][e] = sum_d rel_q[h,r,d] * Wk[h*64+d][e]   (for p2c)
//  z=2 (blocks 0,1): b3[hr] = rel_k[h,r,:].bq_head ; b2 from rel_q,bk (f32)
// ---------------------------------------------------------------------------
__global__ __launch_bounds__(256)
void wprep_kernel(const float* __restrict__ Wq, const float* __restrict__ bq,
                  const float* __restrict__ Wk, const float* __restrict__ bk,
                  const float* __restrict__ RelK, const float* __restrict__ RelQ,
                  u16* __restrict__ W3, float* __restrict__ b3,
                  u16* __restrict__ W2, float* __restrict__ b2)
{
    const int z = blockIdx.y;
    const int t = threadIdx.x;

    if (z == 2) {
        if (blockIdx.x >= 2) return;
        const float* rel  = blockIdx.x ? RelQ : RelK;
        const float* bias = blockIdx.x ? bk : bq;
        float* out        = blockIdx.x ? b2 : b3;
        for (int hr = t; hr < 512; hr += 256) {
            int h = hr >> 6, r = hr & 63;
            float s = 0.f;
            #pragma unroll 8
            for (int d = 0; d < 64; ++d)
                s += rel[((size_t)h * NR + r) * NDK + d] * bias[h * 64 + d];
            out[hr] = s;
        }
        return;
    }

    const float* rel = z ? RelQ : RelK;   // [8][64][64]
    const float* W   = z ? Wk : Wq;       // [512][512]
    u16* Wout        = z ? W2 : W3;

    const int h  = blockIdx.x >> 3;
    const int e0 = (blockIdx.x & 7) * 64;

    __shared__ float At[64][68];   // At[d][r]
    __shared__ float Bs[64][68];   // Bs[d][e]

    const int ty = t >> 4, tx = t & 15;

    #pragma unroll
    for (int pass = 0; pass < 4; ++pass) {
        {
            int lr = t >> 2, lk = (t & 3) << 2;
            f32x4 a = *(const f32x4*)&rel[((size_t)h * NR + lr) * NDK + pass * 16 + lk];
            At[pass*16 + lk + 0][lr] = a.x; At[pass*16 + lk + 1][lr] = a.y;
            At[pass*16 + lk + 2][lr] = a.z; At[pass*16 + lk + 3][lr] = a.w;
        }
        {
            int dr = t >> 4, ec = (t & 15) << 2;
            *(f32x4*)&Bs[pass*16 + dr][ec] =
                *(const f32x4*)&W[(size_t)(h*64 + pass*16 + dr) * ND + e0 + ec];
        }
    }
    __syncthreads();

    float acc[4][4] = {{0.f,0.f,0.f,0.f},{0.f,0.f,0.f,0.f},
                       {0.f,0.f,0.f,0.f},{0.f,0.f,0.f,0.f}};
    #pragma unroll 16
    for (int kk = 0; kk < 64; ++kk) {
        f32x4 a4 = *(const f32x4*)&At[kk][ty*4];
        f32x4 b4 = *(const f32x4*)&Bs[kk][tx*4];
        #pragma unroll
        for (int i = 0; i < 4; ++i) {
            acc[i][0] += a4[i]*b4.x; acc[i][1] += a4[i]*b4.y;
            acc[i][2] += a4[i]*b4.z; acc[i][3] += a4[i]*b4.w;
        }
    }

    #pragma unroll
    for (int i = 0; i < 4; ++i) {
        u16x4 o;
        o.x = f2bf(acc[i][0]); o.y = f2bf(acc[i][1]);
        o.z = f2bf(acc[i][2]); o.w = f2bf(acc[i][3]);
        *(u16x4*)&Wout[(size_t)(h*64 + ty*4 + i) * ND + e0 + tx*4] = o;
    }
}

// ---------------------------------------------------------------------------
// Kernel C: batched projection via MFMA (no LDS).   (round-10 exact)
//  z=0 q->bf16, z=1 k->bf16, z=2 v->bf16, z=3 c2p->f32, z=4 p2c->bf16.
// Block = 64 rows x 64 cols (one head); 4 waves.
// D layout (m89-verified): row=(lane>>4)*4+reg, col=lane&15.
// ---------------------------------------------------------------------------
__global__ __launch_bounds__(256)
void gemm5_mfma_kernel(const u16* __restrict__ xq, const u16* __restrict__ xk,
                       const u16* __restrict__ xv,
                       const u16* __restrict__ wq, const u16* __restrict__ wk,
                       const u16* __restrict__ wv, const u16* __restrict__ w3,
                       const u16* __restrict__ w2,
                       const float* __restrict__ bq, const float* __restrict__ bk,
                       const float* __restrict__ bv, const float* __restrict__ b3,
                       const float* __restrict__ b2,
                       u16* __restrict__ qbf, u16* __restrict__ kbf,
                       u16* __restrict__ vbf, float* __restrict__ c2p,
                       u16* __restrict__ p2cb)
{
    const int z = blockIdx.z;
    const u16* __restrict__ X = (z==0 || z==3) ? xq : ((z==1 || z==4) ? xk : xv);
    const u16* __restrict__ W = (z==0)?wq:(z==1)?wk:(z==2)?wv:(z==3)?w3:w2;
    const float* __restrict__ bias = (z==0)?bq:(z==1)?bk:(z==2)?bv:(z==3)?b3:b2;

    const int t    = threadIdx.x;
    const int wv_  = t >> 6;
    const int lane = t & 63;
    const int lr   = lane & 15;
    const int kg   = lane >> 4;

    const int m0 = blockIdx.x * 64 + wv_ * 16;
    const int h  = blockIdx.y;
    const int n0 = h * 64;

    const u16* Ap = X + (size_t)(m0 + lr) * ND + kg * 8;
    const u16* Bp = W + (size_t)(n0 + lr) * ND + kg * 8;

    f32x4 acc[4] = {{0,0,0,0},{0,0,0,0},{0,0,0,0},{0,0,0,0}};

    for (int kt = 0; kt < 16; ++kt) {
        s16x8 a = *(const s16x8*)(Ap + kt * 32);
        #pragma unroll
        for (int nt = 0; nt < 4; ++nt) {
            s16x8 b = *(const s16x8*)(Bp + (size_t)nt * 16 * ND + kt * 32);
            acc[nt] = __builtin_amdgcn_mfma_f32_16x16x32_bf16(a, b, acc[nt], 0, 0, 0);
        }
    }

    #pragma unroll
    for (int nt = 0; nt < 4; ++nt) {
        const int col = n0 + nt * 16 + lr;
        const float bb = bias[col];
        #pragma unroll
        for (int r = 0; r < 4; ++r) {
            int row = m0 + kg * 4 + r;
            int bI  = row >> 8;
            int lI  = row & 255;
            size_t oidx = (((size_t)(bI * NH + h)) * NL + lI) * 64 + nt * 16 + lr;
            float val = acc[nt][r] + bb;
            if      (z == 0) qbf[oidx]  = f2bf(val);
            else if (z == 1) kbf[oidx]  = f2bf(val);
            else if (z == 2) vbf[oidx]  = f2bf(val);
            else if (z == 3) c2p[oidx]  = val;
            else             p2cb[oidx] = f2bf(val);
        }
    }
}

// ---------------------------------------------------------------------------
// Kernel D: scores + gathers + softmax -> p  (round-10 except p now bf16)
// Block = (16 l-rows, bh), 256 thr (4 waves), grid (16,32)=512.
// ---------------------------------------------------------------------------
__global__ __launch_bounds__(256)
void scores_kernel(const u16* __restrict__ qbf, const u16* __restrict__ kbf,
                   const float* __restrict__ C2P, const u16* __restrict__ P2Cb,
                   const int* __restrict__ RelPos, const void* __restrict__ MaskP,
                   u16* __restrict__ Pout)
{
    const int bh = blockIdx.y;
    const int b  = bh >> 3;
    const int l0 = blockIdx.x * 16;
    const int t  = threadIdx.x;

    __shared__ float sc[16][257];     // scores -> p   (16.4 KB)
    __shared__ u16   psall[256][68];  // p2c bf16      (34.8 KB, padded)
    __shared__ float cs[16][68];      // c2p           (4.3 KB, padded)
    __shared__ float maskv[256];      // mask row      (1 KB)

    // ---- detect mask buffer layout (bool-u8 / f32 / i32), deterministic ----
    const unsigned char* mu = (const unsigned char*)MaskP;
    int loc1  = mu[t*4 + 1];
    int loc23 = mu[t*4 + 2] | mu[t*4 + 3];
    int any1  = __syncthreads_or(loc1);
    int any23 = __syncthreads_or(loc23);
    const int mlayout = any1 ? 0 : (any23 ? 1 : 2);  // 0=u8, 1=f32, 2=i32

    {
        float mval;
        if (mlayout == 0)      mval = (float)mu[b * NL + t];
        else if (mlayout == 1) mval = ((const float*)MaskP)[b * NL + t];
        else                   mval = (float)((const int*)MaskP)[b * NL + t];
        maskv[t] = mval;
        // c2p rows of this l-tile: row = t>>4, f32x4 col (t&15)*4
        *(f32x4*)&cs[t >> 4][(t & 15) * 4] =
            *(const f32x4*)&C2P[(((size_t)bh * NL) + l0 + (t >> 4)) * NR + (t & 15) * 4];
    }

    // ---- stage p2c[b,h]: 256x64 bf16, 2048 x 16B coalesced reads ----
    #pragma unroll
    for (int rep = 0; rep < 8; ++rep) {
        int e = t + rep * 256;           // 0..2047
        *(u16x8*)&psall[e >> 3][(e & 7) * 8] =
            *(const u16x8*)&P2Cb[((size_t)bh * NL + (e >> 3)) * 64 + (e & 7) * 8];
    }

    // ---- QK^T MFMA: wave w owns m-stripe w*64 (four 16-col tiles) ----
    {
        const int wv_  = t >> 6;
        const int lane = t & 63;
        const int lr   = lane & 15;
        const int kg   = lane >> 4;
        const u16* Ap = qbf + ((size_t)bh * NL + l0 + lr) * 64 + kg * 8;
        s16x8 a0 = *(const s16x8*)Ap;
        s16x8 a1 = *(const s16x8*)(Ap + 32);
        #pragma unroll
        for (int c = 0; c < 4; ++c) {
            int m0 = wv_ * 64 + c * 16;
            const u16* Bp = kbf + ((size_t)bh * NL + m0 + lr) * 64 + kg * 8;
            s16x8 b0 = *(const s16x8*)Bp;
            s16x8 b1 = *(const s16x8*)(Bp + 32);
            f32x4 acc = {0.f, 0.f, 0.f, 0.f};
            acc = __builtin_amdgcn_mfma_f32_16x16x32_bf16(a0, b0, acc, 0, 0, 0);
            acc = __builtin_amdgcn_mfma_f32_16x16x32_bf16(a1, b1, acc, 0, 0, 0);
            #pragma unroll
            for (int r = 0; r < 4; ++r)
                sc[kg * 4 + r][m0 + lr] = acc[r];
        }
    }
    __syncthreads();

    // ---- Phase B: gather + scale + mask (barrier-free) ----
    const int i  = t >> 4;        // row 0..15
    const int jj = t & 15;        // lane 0..15
    {
        const size_t rowbase = ((size_t)b * NL + l0 + i) * NL;
        #pragma unroll
        for (int s = 0; s < 16; ++s) {
            const int m = s * 16 + jj;
            int r = RelPos[rowbase + m];
            float val = sc[i][m] + cs[i][r] + bf2f(psall[m][r]);
            val *= (1.0f / 24.0f);   // 1 / (3 * sqrt(64))
            if (maskv[m] != 0.0f) val = -1e9f;
            sc[i][m] = val;          // same thread re-reads below
        }
    }

    // ---- Phase C: softmax (16 lanes per row, barrier-free) + p write ----
    {
        float mx = -INFINITY;
        #pragma unroll
        for (int s = 0; s < 16; ++s) mx = fmaxf(mx, sc[i][jj + 16*s]);
        #pragma unroll
        for (int off = 8; off >= 1; off >>= 1) mx = fmaxf(mx, __shfl_xor(mx, off, 16));

        float sum = 0.f;
        float ev[16];
        #pragma unroll
        for (int s = 0; s < 16; ++s) {
            ev[s] = __expf(sc[i][jj + 16*s] - mx);
            sum += ev[s];
        }
        #pragma unroll
        for (int off = 8; off >= 1; off >>= 1) sum += __shfl_xor(sum, off, 16);
        float inv = 1.0f / sum;

        u16* prow = Pout + ((size_t)bh * NL + l0 + i) * NL;
        #pragma unroll
        for (int s = 0; s < 16; ++s)
            prow[jj + 16*s] = f2bf(ev[s] * inv);
    }
}

// ---------------------------------------------------------------------------
// Kernel E: ctx.  ctx[b,h,l,d] = sum_m p * (v + rel_v).
// One block per (b,l); streams the 512 KB rel_v slice (nontemporal).
// CHANGES vs round 10: p read as bf16 (8B staged loads, cvt once into LDS);
// XCD-bijective swizzle (xcd=bid&7 -> b=xcd>>1) so V[b]+p[b] (2 MB bf16)
// stay resident in that XCD's 4 MB L2 under the stream.
// ---------------------------------------------------------------------------
__global__ __launch_bounds__(256)
void ctx_kernel(const u16* __restrict__ P, const u16* __restrict__ V,
                const float* __restrict__ RV, u16* __restrict__ CTXB)
{
    const int bid = blockIdx.x;
    const int xcd = bid & 7;
    const int b   = xcd >> 1;
    const int l   = (xcd & 1) * 128 + (bid >> 3);
    const int bl  = b * NL + l;
    const int t   = threadIdx.x;

    __shared__ float pw[8][260];   // padded: bank(hc*260+m) distinct per hc
    __shared__ f32x4 redv[128];

    #pragma unroll
    for (int rep = 0; rep < 2; ++rep) {
        int e = t + rep * 256;     // 0..511; u16x4 (8B) each
        u16x4 pv = *(const u16x4*)&P[(((size_t)(b*NH + (e >> 6)) * NL) + l) * NL + (e & 63) * 4];
        int h = e >> 6, c = (e & 63) * 4;
        pw[h][c+0] = bf2f(pv.x); pw[h][c+1] = bf2f(pv.y);
        pw[h][c+2] = bf2f(pv.z); pw[h][c+3] = bf2f(pv.w);
    }
    __syncthreads();

    const int c    = t & 127;    // float4-column 0..127 (head = c>>4)
    const int half = t >> 7;     // m parity
    const int hc   = c >> 4;
    const int dk4  = c & 15;

    const f32x4* rv4 = (const f32x4*)RV + (size_t)bl * NL * 128 + c;
    const u16*   vvp = V + ((size_t)(b*NH + hc) * NL) * 64 + dk4 * 4;

    f32x4 acc = {0.f, 0.f, 0.f, 0.f};
    #pragma unroll 4
    for (int m = half; m < NL; m += 2) {
        float  w  = pw[hc][m];
        f32x4 rv = __builtin_nontemporal_load(rv4 + (size_t)m * 128);
        u16x4 vw = *(const u16x4*)(vvp + (size_t)m * 64);
        acc.x += w * (rv.x + bf2f(vw.x));
        acc.y += w * (rv.y + bf2f(vw.y));
        acc.z += w * (rv.z + bf2f(vw.z));
        acc.w += w * (rv.w + bf2f(vw.w));
    }

    if (half) redv[c] = acc;
    __syncthreads();
    if (!half) {
        f32x4 r2 = redv[c];
        acc.x += r2.x; acc.y += r2.y; acc.z += r2.z; acc.w += r2.w;
        u16x4 o;
        o.x = f2bf(acc.x); o.y = f2bf(acc.y); o.z = f2bf(acc.z); o.w = f2bf(acc.w);
        *(u16x4*)&CTXB[(size_t)bl * ND + c*4] = o;
    }
}

// ---------------------------------------------------------------------------
// Kernel F: out = ctx @ Wo^T + bo via MFMA.  32x64 tiles, grid (32,8)=256.
// wave w: rows (w&1)*16, cols (w>>1)*32.   (round-10 exact)
// ---------------------------------------------------------------------------
__global__ __launch_bounds__(256)
void out_proj_mfma_kernel(const u16* __restrict__ A, const u16* __restrict__ W,
                          const float* __restrict__ bias, float* __restrict__ C)
{
    const int t    = threadIdx.x;
    const int wv_  = t >> 6;
    const int lane = t & 63;
    const int lr   = lane & 15;
    const int kg   = lane >> 4;

    const int m0 = blockIdx.x * 32 + (wv_ & 1) * 16;
    const int n0 = blockIdx.y * 64 + (wv_ >> 1) * 32;

    const u16* Ap = A + (size_t)(m0 + lr) * ND + kg * 8;
    const u16* Bp = W + (size_t)(n0 + lr) * ND + kg * 8;

    f32x4 acc[2] = {{0,0,0,0},{0,0,0,0}};

    for (int kt = 0; kt < 16; ++kt) {
        s16x8 a = *(const s16x8*)(Ap + kt * 32);
        #pragma unroll
        for (int nt = 0; nt < 2; ++nt) {
            s16x8 b = *(const s16x8*)(Bp + (size_t)nt * 16 * ND + kt * 32);
            acc[nt] = __builtin_amdgcn_mfma_f32_16x16x32_bf16(a, b, acc[nt], 0, 0, 0);
        }
    }

    #pragma unroll
    for (int nt = 0; nt < 2; ++nt) {
        const int col = n0 + nt * 16 + lr;
        const float bb = bias[col];
        #pragma unroll
        for (int r = 0; r < 4; ++r) {
            int row = m0 + kg * 4 + r;
            C[(size_t)row * ND + col] = acc[nt][r] + bb;
        }
    }
}

// ---------------------------------------------------------------------------
extern "C" void kernel_launch(void* const* d_in, const int* in_sizes, int n_in,
                              void* d_out, int out_size, void* d_ws, size_t ws_size,
                              hipStream_t stream)
{
    const float* query   = (const float*)d_in[0];
    const float* key     = (const float*)d_in[1];
    const float* value   = (const float*)d_in[2];
    const void*  mask    = d_in[3];
    const int*   rel_pos = (const int*)d_in[4];
    const float* rel_q   = (const float*)d_in[5];
    const float* rel_k   = (const float*)d_in[6];
    const float* rel_v   = (const float*)d_in[7];
    const float* Wq = (const float*)d_in[8];
    const float* bq = (const float*)d_in[9];
    const float* Wk = (const float*)d_in[10];
    const float* bk = (const float*)d_in[11];
    const float* Wv = (const float*)d_in[12];
    const float* bv = (const float*)d_in[13];
    const float* Wo = (const float*)d_in[14];
    const float* bo = (const float*)d_in[15];

    // ---- workspace layout ----
    float* wsf  = (float*)d_ws;
    float* c2p  = wsf;                    // 524288 f32
    float* b3   = c2p + 524288;           // 512 f32
    float* b2   = b3 + 512;               // 512 f32
    u16* wsu  = (u16*)(b2 + 512);
    u16* xqb  = wsu;                      // 524288 u16
    u16* xkb  = xqb + 524288;
    u16* xvb  = xkb + 524288;
    u16* wqb  = xvb + 524288;             // 262144 u16
    u16* wkb  = wqb + 262144;
    u16* wvb  = wkb + 262144;
    u16* wob  = wvb + 262144;
    u16* w3b  = wob + 262144;
    u16* w2b  = w3b + 262144;
    u16* qbf  = w2b + 262144;             // 524288 u16
    u16* kbf  = qbf + 524288;
    u16* vbf  = kbf + 524288;             // 524288 u16 (bf16 V)
    u16* p2cb = vbf + 524288;             // 524288 u16 [B,H,M,64]
    u16* pb   = p2cb + 524288;            // 2097152 u16 [B,H,L,M] (bf16 p)
    u16* ctxb = pb + 2097152;             // 524288 u16

    convert_bf16_kernel<<<dim3(512, 7), 256, 0, stream>>>(
        query, key, value, Wq, Wk, Wv, Wo, xqb, xkb, xvb, wqb, wkb, wvb, wob);

    wprep_kernel<<<dim3(64, 3), 256, 0, stream>>>(
        Wq, bq, Wk, bk, rel_k, rel_q, w3b, b3, w2b, b2);

    gemm5_mfma_kernel<<<dim3(16, 8, 5), 256, 0, stream>>>(
        xqb, xkb, xvb, wqb, wkb, wvb, w3b, w2b,
        bq, bk, bv, b3, b2, qbf, kbf, vbf, c2p, p2cb);

    scores_kernel<<<dim3(16, 32), 256, 0, stream>>>(
        qbf, kbf, c2p, p2cb, rel_pos, mask, pb);

    ctx_kernel<<<dim3(1024), 256, 0, stream>>>(pb, vbf, rel_v, ctxb);

    out_proj_mfma_kernel<<<dim3(32, 8), 256, 0, stream>>>(ctxb, wob, bo, (float*)d_out);
}

// Round 12
// 145.607 us; speedup vs baseline: 1.1161x; 1.1161x over previous
//
#include <hip/hip_runtime.h>
#include <hip/hip_bf16.h>
#include <math.h>

#define NB 4
#define NL 256
#define ND 512
#define NH 8
#define NR 64
#define NDK 64

typedef float f32x4 __attribute__((ext_vector_type(4)));
typedef short s16x8 __attribute__((ext_vector_type(8)));
typedef unsigned short u16;
typedef u16 u16x4 __attribute__((ext_vector_type(4)));
typedef u16 u16x8 __attribute__((ext_vector_type(8)));
typedef unsigned int u32;

static __device__ __forceinline__ u16 f2bf(float f) {
    __hip_bfloat16 h = __float2bfloat16(f);   // RNE
    return __builtin_bit_cast(unsigned short, h);
}
static __device__ __forceinline__ float bf2f(u16 u) {
    return __builtin_bit_cast(float, (u32)u << 16);
}

// ---------------------------------------------------------------------------
// Kernel A: convert inputs + weights f32 -> bf16.   (round-10 exact)
// jobs: 0 query, 1 key, 2 value (524288 ea); 3 Wq, 4 Wk, 5 Wv, 6 Wo (262144).
// ---------------------------------------------------------------------------
__global__ __launch_bounds__(256)
void convert_bf16_kernel(const float* __restrict__ q, const float* __restrict__ k,
                         const float* __restrict__ v, const float* __restrict__ wq,
                         const float* __restrict__ wk, const float* __restrict__ wv,
                         const float* __restrict__ wo,
                         u16* __restrict__ oq, u16* __restrict__ ok, u16* __restrict__ ov,
                         u16* __restrict__ owq, u16* __restrict__ owk,
                         u16* __restrict__ owv, u16* __restrict__ owo)
{
    const int job = blockIdx.y;
    const float* src; u16* dst; int n;
    switch (job) {
        case 0: src = q;  dst = oq;  n = 524288; break;
        case 1: src = k;  dst = ok;  n = 524288; break;
        case 2: src = v;  dst = ov;  n = 524288; break;
        case 3: src = wq; dst = owq; n = 262144; break;
        case 4: src = wk; dst = owk; n = 262144; break;
        case 5: src = wv; dst = owv; n = 262144; break;
        default: src = wo; dst = owo; n = 262144; break;
    }
    int idx = (blockIdx.x * 256 + threadIdx.x) * 4;
    if (idx >= n) return;
    f32x4 x = *(const f32x4*)&src[idx];
    u16x4 o;
    o.x = f2bf(x.x); o.y = f2bf(x.y); o.z = f2bf(x.z); o.w = f2bf(x.w);
    *(u16x4*)&dst[idx] = o;
}

// ---------------------------------------------------------------------------
// Kernel B: W-prep (f32 compute, bf16 out).   (round-10 exact)
//  z=0: W3[h*64+r][e] = sum_d rel_k[h,r,d] * Wq[h*64+d][e]   (for c2p)
//  z=1: W2[h*64+r][e] = sum_d rel_q[h,r,d] * Wk[h*64+d][e]   (for p2c)
//  z=2 (blocks 0,1): b3[hr] = rel_k[h,r,:].bq_head ; b2 from rel_q,bk (f32)
// ---------------------------------------------------------------------------
__global__ __launch_bounds__(256)
void wprep_kernel(const float* __restrict__ Wq, const float* __restrict__ bq,
                  const float* __restrict__ Wk, const float* __restrict__ bk,
                  const float* __restrict__ RelK, const float* __restrict__ RelQ,
                  u16* __restrict__ W3, float* __restrict__ b3,
                  u16* __restrict__ W2, float* __restrict__ b2)
{
    const int z = blockIdx.y;
    const int t = threadIdx.x;

    if (z == 2) {
        if (blockIdx.x >= 2) return;
        const float* rel  = blockIdx.x ? RelQ : RelK;
        const float* bias = blockIdx.x ? bk : bq;
        float* out        = blockIdx.x ? b2 : b3;
        for (int hr = t; hr < 512; hr += 256) {
            int h = hr >> 6, r = hr & 63;
            float s = 0.f;
            #pragma unroll 8
            for (int d = 0; d < 64; ++d)
                s += rel[((size_t)h * NR + r) * NDK + d] * bias[h * 64 + d];
            out[hr] = s;
        }
        return;
    }

    const float* rel = z ? RelQ : RelK;   // [8][64][64]
    const float* W   = z ? Wk : Wq;       // [512][512]
    u16* Wout        = z ? W2 : W3;

    const int h  = blockIdx.x >> 3;
    const int e0 = (blockIdx.x & 7) * 64;

    __shared__ float At[64][68];   // At[d][r]
    __shared__ float Bs[64][68];   // Bs[d][e]

    const int ty = t >> 4, tx = t & 15;

    #pragma unroll
    for (int pass = 0; pass < 4; ++pass) {
        {
            int lr = t >> 2, lk = (t & 3) << 2;
            f32x4 a = *(const f32x4*)&rel[((size_t)h * NR + lr) * NDK + pass * 16 + lk];
            At[pass*16 + lk + 0][lr] = a.x; At[pass*16 + lk + 1][lr] = a.y;
            At[pass*16 + lk + 2][lr] = a.z; At[pass*16 + lk + 3][lr] = a.w;
        }
        {
            int dr = t >> 4, ec = (t & 15) << 2;
            *(f32x4*)&Bs[pass*16 + dr][ec] =
                *(const f32x4*)&W[(size_t)(h*64 + pass*16 + dr) * ND + e0 + ec];
        }
    }
    __syncthreads();

    float acc[4][4] = {{0.f,0.f,0.f,0.f},{0.f,0.f,0.f,0.f},
                       {0.f,0.f,0.f,0.f},{0.f,0.f,0.f,0.f}};
    #pragma unroll 16
    for (int kk = 0; kk < 64; ++kk) {
        f32x4 a4 = *(const f32x4*)&At[kk][ty*4];
        f32x4 b4 = *(const f32x4*)&Bs[kk][tx*4];
        #pragma unroll
        for (int i = 0; i < 4; ++i) {
            acc[i][0] += a4[i]*b4.x; acc[i][1] += a4[i]*b4.y;
            acc[i][2] += a4[i]*b4.z; acc[i][3] += a4[i]*b4.w;
        }
    }

    #pragma unroll
    for (int i = 0; i < 4; ++i) {
        u16x4 o;
        o.x = f2bf(acc[i][0]); o.y = f2bf(acc[i][1]);
        o.z = f2bf(acc[i][2]); o.w = f2bf(acc[i][3]);
        *(u16x4*)&Wout[(size_t)(h*64 + ty*4 + i) * ND + e0 + tx*4] = o;
    }
}

// ---------------------------------------------------------------------------
// Kernel C: batched projection via MFMA (no LDS).   (round-10 exact)
//  z=0 q->bf16, z=1 k->bf16, z=2 v->bf16, z=3 c2p->f32, z=4 p2c->bf16.
// Block = 64 rows x 64 cols (one head); 4 waves.
// D layout (m89-verified): row=(lane>>4)*4+reg, col=lane&15.
// ---------------------------------------------------------------------------
__global__ __launch_bounds__(256)
void gemm5_mfma_kernel(const u16* __restrict__ xq, const u16* __restrict__ xk,
                       const u16* __restrict__ xv,
                       const u16* __restrict__ wq, const u16* __restrict__ wk,
                       const u16* __restrict__ wv, const u16* __restrict__ w3,
                       const u16* __restrict__ w2,
                       const float* __restrict__ bq, const float* __restrict__ bk,
                       const float* __restrict__ bv, const float* __restrict__ b3,
                       const float* __restrict__ b2,
                       u16* __restrict__ qbf, u16* __restrict__ kbf,
                       u16* __restrict__ vbf, float* __restrict__ c2p,
                       u16* __restrict__ p2cb)
{
    const int z = blockIdx.z;
    const u16* __restrict__ X = (z==0 || z==3) ? xq : ((z==1 || z==4) ? xk : xv);
    const u16* __restrict__ W = (z==0)?wq:(z==1)?wk:(z==2)?wv:(z==3)?w3:w2;
    const float* __restrict__ bias = (z==0)?bq:(z==1)?bk:(z==2)?bv:(z==3)?b3:b2;

    const int t    = threadIdx.x;
    const int wv_  = t >> 6;
    const int lane = t & 63;
    const int lr   = lane & 15;
    const int kg   = lane >> 4;

    const int m0 = blockIdx.x * 64 + wv_ * 16;
    const int h  = blockIdx.y;
    const int n0 = h * 64;

    const u16* Ap = X + (size_t)(m0 + lr) * ND + kg * 8;
    const u16* Bp = W + (size_t)(n0 + lr) * ND + kg * 8;

    f32x4 acc[4] = {{0,0,0,0},{0,0,0,0},{0,0,0,0},{0,0,0,0}};

    for (int kt = 0; kt < 16; ++kt) {
        s16x8 a = *(const s16x8*)(Ap + kt * 32);
        #pragma unroll
        for (int nt = 0; nt < 4; ++nt) {
            s16x8 b = *(const s16x8*)(Bp + (size_t)nt * 16 * ND + kt * 32);
            acc[nt] = __builtin_amdgcn_mfma_f32_16x16x32_bf16(a, b, acc[nt], 0, 0, 0);
        }
    }

    #pragma unroll
    for (int nt = 0; nt < 4; ++nt) {
        const int col = n0 + nt * 16 + lr;
        const float bb = bias[col];
        #pragma unroll
        for (int r = 0; r < 4; ++r) {
            int row = m0 + kg * 4 + r;
            int bI  = row >> 8;
            int lI  = row & 255;
            size_t oidx = (((size_t)(bI * NH + h)) * NL + lI) * 64 + nt * 16 + lr;
            float val = acc[nt][r] + bb;
            if      (z == 0) qbf[oidx]  = f2bf(val);
            else if (z == 1) kbf[oidx]  = f2bf(val);
            else if (z == 2) vbf[oidx]  = f2bf(val);
            else if (z == 3) c2p[oidx]  = val;
            else             p2cb[oidx] = f2bf(val);
        }
    }
}

// ---------------------------------------------------------------------------
// Kernel D: scores + gathers + softmax -> p bf16 [B,H,L,M]
// (round-10 exact except the p write is bf16)
// Block = (16 l-rows, bh), 256 thr (4 waves), grid (16,32)=512.
// ---------------------------------------------------------------------------
__global__ __launch_bounds__(256)
void scores_kernel(const u16* __restrict__ qbf, const u16* __restrict__ kbf,
                   const float* __restrict__ C2P, const u16* __restrict__ P2Cb,
                   const int* __restrict__ RelPos, const void* __restrict__ MaskP,
                   u16* __restrict__ Pout)
{
    const int bh = blockIdx.y;
    const int b  = bh >> 3;
    const int l0 = blockIdx.x * 16;
    const int t  = threadIdx.x;

    __shared__ float sc[16][257];     // scores -> p   (16.4 KB)
    __shared__ u16   psall[256][68];  // p2c bf16      (34.8 KB, padded)
    __shared__ float cs[16][68];      // c2p           (4.3 KB, padded)
    __shared__ float maskv[256];      // mask row      (1 KB)

    // ---- detect mask buffer layout (bool-u8 / f32 / i32), deterministic ----
    const unsigned char* mu = (const unsigned char*)MaskP;
    int loc1  = mu[t*4 + 1];
    int loc23 = mu[t*4 + 2] | mu[t*4 + 3];
    int any1  = __syncthreads_or(loc1);
    int any23 = __syncthreads_or(loc23);
    const int mlayout = any1 ? 0 : (any23 ? 1 : 2);  // 0=u8, 1=f32, 2=i32

    {
        float mval;
        if (mlayout == 0)      mval = (float)mu[b * NL + t];
        else if (mlayout == 1) mval = ((const float*)MaskP)[b * NL + t];
        else                   mval = (float)((const int*)MaskP)[b * NL + t];
        maskv[t] = mval;
        // c2p rows of this l-tile: row = t>>4, f32x4 col (t&15)*4
        *(f32x4*)&cs[t >> 4][(t & 15) * 4] =
            *(const f32x4*)&C2P[(((size_t)bh * NL) + l0 + (t >> 4)) * NR + (t & 15) * 4];
    }

    // ---- stage p2c[b,h]: 256x64 bf16, 2048 x 16B coalesced reads ----
    #pragma unroll
    for (int rep = 0; rep < 8; ++rep) {
        int e = t + rep * 256;           // 0..2047
        *(u16x8*)&psall[e >> 3][(e & 7) * 8] =
            *(const u16x8*)&P2Cb[((size_t)bh * NL + (e >> 3)) * 64 + (e & 7) * 8];
    }

    // ---- QK^T MFMA: wave w owns m-stripe w*64 (four 16-col tiles) ----
    {
        const int wv_  = t >> 6;
        const int lane = t & 63;
        const int lr   = lane & 15;
        const int kg   = lane >> 4;
        const u16* Ap = qbf + ((size_t)bh * NL + l0 + lr) * 64 + kg * 8;
        s16x8 a0 = *(const s16x8*)Ap;
        s16x8 a1 = *(const s16x8*)(Ap + 32);
        #pragma unroll
        for (int c = 0; c < 4; ++c) {
            int m0 = wv_ * 64 + c * 16;
            const u16* Bp = kbf + ((size_t)bh * NL + m0 + lr) * 64 + kg * 8;
            s16x8 b0 = *(const s16x8*)Bp;
            s16x8 b1 = *(const s16x8*)(Bp + 32);
            f32x4 acc = {0.f, 0.f, 0.f, 0.f};
            acc = __builtin_amdgcn_mfma_f32_16x16x32_bf16(a0, b0, acc, 0, 0, 0);
            acc = __builtin_amdgcn_mfma_f32_16x16x32_bf16(a1, b1, acc, 0, 0, 0);
            #pragma unroll
            for (int r = 0; r < 4; ++r)
                sc[kg * 4 + r][m0 + lr] = acc[r];
        }
    }
    __syncthreads();

    // ---- Phase B: gather + scale + mask (barrier-free) ----
    const int i  = t >> 4;        // row 0..15
    const int jj = t & 15;        // lane 0..15
    {
        const size_t rowbase = ((size_t)b * NL + l0 + i) * NL;
        #pragma unroll
        for (int s = 0; s < 16; ++s) {
            const int m = s * 16 + jj;
            int r = RelPos[rowbase + m];
            float val = sc[i][m] + cs[i][r] + bf2f(psall[m][r]);
            val *= (1.0f / 24.0f);   // 1 / (3 * sqrt(64))
            if (maskv[m] != 0.0f) val = -1e9f;
            sc[i][m] = val;          // same thread re-reads below
        }
    }

    // ---- Phase C: softmax (16 lanes per row, barrier-free) + p write ----
    {
        float mx = -INFINITY;
        #pragma unroll
        for (int s = 0; s < 16; ++s) mx = fmaxf(mx, sc[i][jj + 16*s]);
        #pragma unroll
        for (int off = 8; off >= 1; off >>= 1) mx = fmaxf(mx, __shfl_xor(mx, off, 16));

        float sum = 0.f;
        float ev[16];
        #pragma unroll
        for (int s = 0; s < 16; ++s) {
            ev[s] = __expf(sc[i][jj + 16*s] - mx);
            sum += ev[s];
        }
        #pragma unroll
        for (int off = 8; off >= 1; off >>= 1) sum += __shfl_xor(sum, off, 16);
        float inv = 1.0f / sum;

        u16* prow = Pout + ((size_t)bh * NL + l0 + i) * NL;
        #pragma unroll
        for (int s = 0; s < 16; ++s)
            prow[jj + 16*s] = f2bf(ev[s] * inv);
    }
}

// ---------------------------------------------------------------------------
// Kernel E: ctx.  ctx[b,h,l,d] = sum_m p * (v + rel_v).
// One block per (b,l), NATURAL bl = blockIdx.x mapping (round-10 exact);
// streams the 512 KB rel_v slice (nontemporal).  Only change vs round 10:
// p staged from bf16 (u16x4 loads, cvt once into f32 LDS).
// ---------------------------------------------------------------------------
__global__ __launch_bounds__(256)
void ctx_kernel(const u16* __restrict__ P, const u16* __restrict__ V,
                const float* __restrict__ RV, u16* __restrict__ CTXB)
{
    const int bl = blockIdx.x;
    const int b  = bl >> 8;
    const int l  = bl & 255;
    const int t  = threadIdx.x;

    __shared__ float pw[8][260];   // padded: bank(hc*260+m) distinct per hc
    __shared__ f32x4 redv[128];

    #pragma unroll
    for (int rep = 0; rep < 2; ++rep) {
        int e = t + rep * 256;     // 0..511; u16x4 (8B) each
        int h = e >> 6, c = (e & 63) * 4;
        u16x4 pv = *(const u16x4*)&P[(((size_t)(b*NH + h) * NL) + l) * NL + c];
        pw[h][c+0] = bf2f(pv.x); pw[h][c+1] = bf2f(pv.y);
        pw[h][c+2] = bf2f(pv.z); pw[h][c+3] = bf2f(pv.w);
    }
    __syncthreads();

    const int c    = t & 127;    // float4-column 0..127 (head = c>>4)
    const int half = t >> 7;     // m parity
    const int hc   = c >> 4;
    const int dk4  = c & 15;

    const f32x4* rv4 = (const f32x4*)RV + (size_t)bl * NL * 128 + c;
    const u16*   vvp = V + ((size_t)(b*NH + hc) * NL) * 64 + dk4 * 4;

    f32x4 acc = {0.f, 0.f, 0.f, 0.f};
    #pragma unroll 4
    for (int m = half; m < NL; m += 2) {
        float  w  = pw[hc][m];
        f32x4 rv = __builtin_nontemporal_load(rv4 + (size_t)m * 128);
        u16x4 vw = *(const u16x4*)(vvp + (size_t)m * 64);
        acc.x += w * (rv.x + bf2f(vw.x));
        acc.y += w * (rv.y + bf2f(vw.y));
        acc.z += w * (rv.z + bf2f(vw.z));
        acc.w += w * (rv.w + bf2f(vw.w));
    }

    if (half) redv[c] = acc;
    __syncthreads();
    if (!half) {
        f32x4 r2 = redv[c];
        acc.x += r2.x; acc.y += r2.y; acc.z += r2.z; acc.w += r2.w;
        u16x4 o;
        o.x = f2bf(acc.x); o.y = f2bf(acc.y); o.z = f2bf(acc.z); o.w = f2bf(acc.w);
        *(u16x4*)&CTXB[(size_t)bl * ND + c*4] = o;
    }
}

// ---------------------------------------------------------------------------
// Kernel F: out = ctx @ Wo^T + bo via MFMA.  32x64 tiles, grid (32,8)=256.
// wave w: rows (w&1)*16, cols (w>>1)*32.   (round-10 exact)
// ---------------------------------------------------------------------------
__global__ __launch_bounds__(256)
void out_proj_mfma_kernel(const u16* __restrict__ A, const u16* __restrict__ W,
                          const float* __restrict__ bias, float* __restrict__ C)
{
    const int t    = threadIdx.x;
    const int wv_  = t >> 6;
    const int lane = t & 63;
    const int lr   = lane & 15;
    const int kg   = lane >> 4;

    const int m0 = blockIdx.x * 32 + (wv_ & 1) * 16;
    const int n0 = blockIdx.y * 64 + (wv_ >> 1) * 32;

    const u16* Ap = A + (size_t)(m0 + lr) * ND + kg * 8;
    const u16* Bp = W + (size_t)(n0 + lr) * ND + kg * 8;

    f32x4 acc[2] = {{0,0,0,0},{0,0,0,0}};

    for (int kt = 0; kt < 16; ++kt) {
        s16x8 a = *(const s16x8*)(Ap + kt * 32);
        #pragma unroll
        for (int nt = 0; nt < 2; ++nt) {
            s16x8 b = *(const s16x8*)(Bp + (size_t)nt * 16 * ND + kt * 32);
            acc[nt] = __builtin_amdgcn_mfma_f32_16x16x32_bf16(a, b, acc[nt], 0, 0, 0);
        }
    }

    #pragma unroll
    for (int nt = 0; nt < 2; ++nt) {
        const int col = n0 + nt * 16 + lr;
        const float bb = bias[col];
        #pragma unroll
        for (int r = 0; r < 4; ++r) {
            int row = m0 + kg * 4 + r;
            C[(size_t)row * ND + col] = acc[nt][r] + bb;
        }
    }
}

// ---------------------------------------------------------------------------
extern "C" void kernel_launch(void* const* d_in, const int* in_sizes, int n_in,
                              void* d_out, int out_size, void* d_ws, size_t ws_size,
                              hipStream_t stream)
{
    const float* query   = (const float*)d_in[0];
    const float* key     = (const float*)d_in[1];
    const float* value   = (const float*)d_in[2];
    const void*  mask    = d_in[3];
    const int*   rel_pos = (const int*)d_in[4];
    const float* rel_q   = (const float*)d_in[5];
    const float* rel_k   = (const float*)d_in[6];
    const float* rel_v   = (const float*)d_in[7];
    const float* Wq = (const float*)d_in[8];
    const float* bq = (const float*)d_in[9];
    const float* Wk = (const float*)d_in[10];
    const float* bk = (const float*)d_in[11];
    const float* Wv = (const float*)d_in[12];
    const float* bv = (const float*)d_in[13];
    const float* Wo = (const float*)d_in[14];
    const float* bo = (const float*)d_in[15];

    // ---- workspace layout ----
    float* wsf  = (float*)d_ws;
    float* c2p  = wsf;                    // 524288 f32
    float* b3   = c2p + 524288;           // 512 f32
    float* b2   = b3 + 512;               // 512 f32
    u16* wsu  = (u16*)(b2 + 512);
    u16* xqb  = wsu;                      // 524288 u16
    u16* xkb  = xqb + 524288;
    u16* xvb  = xkb + 524288;
    u16* wqb  = xvb + 524288;             // 262144 u16
    u16* wkb  = wqb + 262144;
    u16* wvb  = wkb + 262144;
    u16* wob  = wvb + 262144;
    u16* w3b  = wob + 262144;
    u16* w2b  = w3b + 262144;
    u16* qbf  = w2b + 262144;             // 524288 u16
    u16* kbf  = qbf + 524288;
    u16* vbf  = kbf + 524288;             // 524288 u16 (bf16 V)
    u16* p2cb = vbf + 524288;             // 524288 u16 [B,H,M,64]
    u16* pb   = p2cb + 524288;            // 2097152 u16 [B,H,L,M] (bf16 p)
    u16* ctxb = pb + 2097152;             // 524288 u16

    convert_bf16_kernel<<<dim3(512, 7), 256, 0, stream>>>(
        query, key, value, Wq, Wk, Wv, Wo, xqb, xkb, xvb, wqb, wkb, wvb, wob);

    wprep_kernel<<<dim3(64, 3), 256, 0, stream>>>(
        Wq, bq, Wk, bk, rel_k, rel_q, w3b, b3, w2b, b2);

    gemm5_mfma_kernel<<<dim3(16, 8, 5), 256, 0, stream>>>(
        xqb, xkb, xvb, wqb, wkb, wvb, w3b, w2b,
        bq, bk, bv, b3, b2, qbf, kbf, vbf, c2p, p2cb);

    scores_kernel<<<dim3(16, 32), 256, 0, stream>>>(
        qbf, kbf, c2p, p2cb, rel_pos, mask, pb);

    ctx_kernel<<<dim3(1024), 256, 0, stream>>>(pb, vbf, rel_v, ctxb);

    out_proj_mfma_kernel<<<dim3(32, 8), 256, 0, stream>>>(ctxb, wob, bo, (float*)d_out);
}

// Round 13
// 143.796 us; speedup vs baseline: 1.1302x; 1.0126x over previous
//
#include <hip/hip_runtime.h>
#include <hip/hip_bf16.h>
#include <math.h>

#define NB 4
#define NL 256
#define ND 512
#define NH 8
#define NR 64
#define NDK 64

typedef float f32x4 __attribute__((ext_vector_type(4)));
typedef short s16x8 __attribute__((ext_vector_type(8)));
typedef unsigned short u16;
typedef u16 u16x4 __attribute__((ext_vector_type(4)));
typedef u16 u16x8 __attribute__((ext_vector_type(8)));
typedef unsigned int u32;

static __device__ __forceinline__ u16 f2bf(float f) {
    __hip_bfloat16 h = __float2bfloat16(f);   // RNE
    return __builtin_bit_cast(unsigned short, h);
}
static __device__ __forceinline__ float bf2f(u16 u) {
    return __builtin_bit_cast(float, (u32)u << 16);
}

// ---------------------------------------------------------------------------
// Kernel A (MERGED convert + wprep): blockIdx.y = job.
//  jobs 0-2: convert query/key/value f32->bf16 (524288 elems, 512 blocks)
//  jobs 3-6: convert Wq/Wk/Wv/Wo f32->bf16 (262144 elems, 256 blocks used)
//  jobs 7-8: W3 = rel_k x Wq_head / W2 = rel_q x Wk_head (bf16 out, 64 blocks)
//  job  9  : b3/b2 bias dots (2 blocks)
// ---------------------------------------------------------------------------
__global__ __launch_bounds__(256)
void prep_kernel(const float* __restrict__ q, const float* __restrict__ k,
                 const float* __restrict__ v,
                 const float* __restrict__ Wq, const float* __restrict__ bq,
                 const float* __restrict__ Wk, const float* __restrict__ bk,
                 const float* __restrict__ Wv, const float* __restrict__ Wo,
                 const float* __restrict__ RelK, const float* __restrict__ RelQ,
                 u16* __restrict__ oq, u16* __restrict__ ok, u16* __restrict__ ov,
                 u16* __restrict__ owq, u16* __restrict__ owk,
                 u16* __restrict__ owv, u16* __restrict__ owo,
                 u16* __restrict__ W3, float* __restrict__ b3,
                 u16* __restrict__ W2, float* __restrict__ b2)
{
    const int job = blockIdx.y;
    const int t   = threadIdx.x;

    __shared__ float At[64][68];   // wprep branch only
    __shared__ float Bs[64][68];

    if (job < 7) {
        const float* src; u16* dst; int n;
        switch (job) {
            case 0: src = q;  dst = oq;  n = 524288; break;
            case 1: src = k;  dst = ok;  n = 524288; break;
            case 2: src = v;  dst = ov;  n = 524288; break;
            case 3: src = Wq; dst = owq; n = 262144; break;
            case 4: src = Wk; dst = owk; n = 262144; break;
            case 5: src = Wv; dst = owv; n = 262144; break;
            default: src = Wo; dst = owo; n = 262144; break;
        }
        int idx = (blockIdx.x * 256 + t) * 4;
        if (idx >= n) return;
        f32x4 x = *(const f32x4*)&src[idx];
        u16x4 o;
        o.x = f2bf(x.x); o.y = f2bf(x.y); o.z = f2bf(x.z); o.w = f2bf(x.w);
        *(u16x4*)&dst[idx] = o;
        return;
    }

    if (job == 9) {
        if (blockIdx.x >= 2) return;
        const float* rel  = blockIdx.x ? RelQ : RelK;
        const float* bias = blockIdx.x ? bk : bq;
        float* out        = blockIdx.x ? b2 : b3;
        for (int hr = t; hr < 512; hr += 256) {
            int h = hr >> 6, r = hr & 63;
            float s = 0.f;
            #pragma unroll 8
            for (int d = 0; d < 64; ++d)
                s += rel[((size_t)h * NR + r) * NDK + d] * bias[h * 64 + d];
            out[hr] = s;
        }
        return;
    }

    // jobs 7,8: W3/W2 GEMM (64 blocks each)
    if (blockIdx.x >= 64) return;
    const int z = job - 7;                 // 0: W3 (rel_k,Wq), 1: W2 (rel_q,Wk)
    const float* rel = z ? RelQ : RelK;    // [8][64][64]
    const float* W   = z ? Wk : Wq;        // [512][512]
    u16* Wout        = z ? W2 : W3;

    const int h  = blockIdx.x >> 3;
    const int e0 = (blockIdx.x & 7) * 64;

    const int ty = t >> 4, tx = t & 15;

    #pragma unroll
    for (int pass = 0; pass < 4; ++pass) {
        {
            int lr = t >> 2, lk = (t & 3) << 2;
            f32x4 a = *(const f32x4*)&rel[((size_t)h * NR + lr) * NDK + pass * 16 + lk];
            At[pass*16 + lk + 0][lr] = a.x; At[pass*16 + lk + 1][lr] = a.y;
            At[pass*16 + lk + 2][lr] = a.z; At[pass*16 + lk + 3][lr] = a.w;
        }
        {
            int dr = t >> 4, ec = (t & 15) << 2;
            *(f32x4*)&Bs[pass*16 + dr][ec] =
                *(const f32x4*)&W[(size_t)(h*64 + pass*16 + dr) * ND + e0 + ec];
        }
    }
    __syncthreads();

    float acc[4][4] = {{0.f,0.f,0.f,0.f},{0.f,0.f,0.f,0.f},
                       {0.f,0.f,0.f,0.f},{0.f,0.f,0.f,0.f}};
    #pragma unroll 16
    for (int kk = 0; kk < 64; ++kk) {
        f32x4 a4 = *(const f32x4*)&At[kk][ty*4];
        f32x4 b4 = *(const f32x4*)&Bs[kk][tx*4];
        #pragma unroll
        for (int i = 0; i < 4; ++i) {
            acc[i][0] += a4[i]*b4.x; acc[i][1] += a4[i]*b4.y;
            acc[i][2] += a4[i]*b4.z; acc[i][3] += a4[i]*b4.w;
        }
    }

    #pragma unroll
    for (int i = 0; i < 4; ++i) {
        u16x4 o;
        o.x = f2bf(acc[i][0]); o.y = f2bf(acc[i][1]);
        o.z = f2bf(acc[i][2]); o.w = f2bf(acc[i][3]);
        *(u16x4*)&Wout[(size_t)(h*64 + ty*4 + i) * ND + e0 + tx*4] = o;
    }
}

// ---------------------------------------------------------------------------
// Kernel C: batched projection via MFMA (no LDS).   (round-12 exact)
//  z=0 q->bf16, z=1 k->bf16, z=2 v->bf16, z=3 c2p->f32, z=4 p2c->bf16.
// Block = 64 rows x 64 cols (one head); 4 waves.
// D layout (m89-verified): row=(lane>>4)*4+reg, col=lane&15.
// ---------------------------------------------------------------------------
__global__ __launch_bounds__(256)
void gemm5_mfma_kernel(const u16* __restrict__ xq, const u16* __restrict__ xk,
                       const u16* __restrict__ xv,
                       const u16* __restrict__ wq, const u16* __restrict__ wk,
                       const u16* __restrict__ wv, const u16* __restrict__ w3,
                       const u16* __restrict__ w2,
                       const float* __restrict__ bq, const float* __restrict__ bk,
                       const float* __restrict__ bv, const float* __restrict__ b3,
                       const float* __restrict__ b2,
                       u16* __restrict__ qbf, u16* __restrict__ kbf,
                       u16* __restrict__ vbf, float* __restrict__ c2p,
                       u16* __restrict__ p2cb)
{
    const int z = blockIdx.z;
    const u16* __restrict__ X = (z==0 || z==3) ? xq : ((z==1 || z==4) ? xk : xv);
    const u16* __restrict__ W = (z==0)?wq:(z==1)?wk:(z==2)?wv:(z==3)?w3:w2;
    const float* __restrict__ bias = (z==0)?bq:(z==1)?bk:(z==2)?bv:(z==3)?b3:b2;

    const int t    = threadIdx.x;
    const int wv_  = t >> 6;
    const int lane = t & 63;
    const int lr   = lane & 15;
    const int kg   = lane >> 4;

    const int m0 = blockIdx.x * 64 + wv_ * 16;
    const int h  = blockIdx.y;
    const int n0 = h * 64;

    const u16* Ap = X + (size_t)(m0 + lr) * ND + kg * 8;
    const u16* Bp = W + (size_t)(n0 + lr) * ND + kg * 8;

    f32x4 acc[4] = {{0,0,0,0},{0,0,0,0},{0,0,0,0},{0,0,0,0}};

    for (int kt = 0; kt < 16; ++kt) {
        s16x8 a = *(const s16x8*)(Ap + kt * 32);
        #pragma unroll
        for (int nt = 0; nt < 4; ++nt) {
            s16x8 b = *(const s16x8*)(Bp + (size_t)nt * 16 * ND + kt * 32);
            acc[nt] = __builtin_amdgcn_mfma_f32_16x16x32_bf16(a, b, acc[nt], 0, 0, 0);
        }
    }

    #pragma unroll
    for (int nt = 0; nt < 4; ++nt) {
        const int col = n0 + nt * 16 + lr;
        const float bb = bias[col];
        #pragma unroll
        for (int r = 0; r < 4; ++r) {
            int row = m0 + kg * 4 + r;
            int bI  = row >> 8;
            int lI  = row & 255;
            size_t oidx = (((size_t)(bI * NH + h)) * NL + lI) * 64 + nt * 16 + lr;
            float val = acc[nt][r] + bb;
            if      (z == 0) qbf[oidx]  = f2bf(val);
            else if (z == 1) kbf[oidx]  = f2bf(val);
            else if (z == 2) vbf[oidx]  = f2bf(val);
            else if (z == 3) c2p[oidx]  = val;
            else             p2cb[oidx] = f2bf(val);
        }
    }
}

// ---------------------------------------------------------------------------
// Kernel D: scores + gathers + softmax -> p bf16 [B,H,L,M]  (round-12 exact)
// Block = (16 l-rows, bh), 256 thr (4 waves), grid (16,32)=512.
// ---------------------------------------------------------------------------
__global__ __launch_bounds__(256)
void scores_kernel(const u16* __restrict__ qbf, const u16* __restrict__ kbf,
                   const float* __restrict__ C2P, const u16* __restrict__ P2Cb,
                   const int* __restrict__ RelPos, const void* __restrict__ MaskP,
                   u16* __restrict__ Pout)
{
    const int bh = blockIdx.y;
    const int b  = bh >> 3;
    const int l0 = blockIdx.x * 16;
    const int t  = threadIdx.x;

    __shared__ float sc[16][257];     // scores -> p   (16.4 KB)
    __shared__ u16   psall[256][68];  // p2c bf16      (34.8 KB, padded)
    __shared__ float cs[16][68];      // c2p           (4.3 KB, padded)
    __shared__ float maskv[256];      // mask row      (1 KB)

    // ---- detect mask buffer layout (bool-u8 / f32 / i32), deterministic ----
    const unsigned char* mu = (const unsigned char*)MaskP;
    int loc1  = mu[t*4 + 1];
    int loc23 = mu[t*4 + 2] | mu[t*4 + 3];
    int any1  = __syncthreads_or(loc1);
    int any23 = __syncthreads_or(loc23);
    const int mlayout = any1 ? 0 : (any23 ? 1 : 2);  // 0=u8, 1=f32, 2=i32

    {
        float mval;
        if (mlayout == 0)      mval = (float)mu[b * NL + t];
        else if (mlayout == 1) mval = ((const float*)MaskP)[b * NL + t];
        else                   mval = (float)((const int*)MaskP)[b * NL + t];
        maskv[t] = mval;
        // c2p rows of this l-tile: row = t>>4, f32x4 col (t&15)*4
        *(f32x4*)&cs[t >> 4][(t & 15) * 4] =
            *(const f32x4*)&C2P[(((size_t)bh * NL) + l0 + (t >> 4)) * NR + (t & 15) * 4];
    }

    // ---- stage p2c[b,h]: 256x64 bf16, 2048 x 16B coalesced reads ----
    #pragma unroll
    for (int rep = 0; rep < 8; ++rep) {
        int e = t + rep * 256;           // 0..2047
        *(u16x8*)&psall[e >> 3][(e & 7) * 8] =
            *(const u16x8*)&P2Cb[((size_t)bh * NL + (e >> 3)) * 64 + (e & 7) * 8];
    }

    // ---- QK^T MFMA: wave w owns m-stripe w*64 (four 16-col tiles) ----
    {
        const int wv_  = t >> 6;
        const int lane = t & 63;
        const int lr   = lane & 15;
        const int kg   = lane >> 4;
        const u16* Ap = qbf + ((size_t)bh * NL + l0 + lr) * 64 + kg * 8;
        s16x8 a0 = *(const s16x8*)Ap;
        s16x8 a1 = *(const s16x8*)(Ap + 32);
        #pragma unroll
        for (int c = 0; c < 4; ++c) {
            int m0 = wv_ * 64 + c * 16;
            const u16* Bp = kbf + ((size_t)bh * NL + m0 + lr) * 64 + kg * 8;
            s16x8 b0 = *(const s16x8*)Bp;
            s16x8 b1 = *(const s16x8*)(Bp + 32);
            f32x4 acc = {0.f, 0.f, 0.f, 0.f};
            acc = __builtin_amdgcn_mfma_f32_16x16x32_bf16(a0, b0, acc, 0, 0, 0);
            acc = __builtin_amdgcn_mfma_f32_16x16x32_bf16(a1, b1, acc, 0, 0, 0);
            #pragma unroll
            for (int r = 0; r < 4; ++r)
                sc[kg * 4 + r][m0 + lr] = acc[r];
        }
    }
    __syncthreads();

    // ---- Phase B: gather + scale + mask (barrier-free) ----
    const int i  = t >> 4;        // row 0..15
    const int jj = t & 15;        // lane 0..15
    {
        const size_t rowbase = ((size_t)b * NL + l0 + i) * NL;
        #pragma unroll
        for (int s = 0; s < 16; ++s) {
            const int m = s * 16 + jj;
            int r = RelPos[rowbase + m];
            float val = sc[i][m] + cs[i][r] + bf2f(psall[m][r]);
            val *= (1.0f / 24.0f);   // 1 / (3 * sqrt(64))
            if (maskv[m] != 0.0f) val = -1e9f;
            sc[i][m] = val;          // same thread re-reads below
        }
    }

    // ---- Phase C: softmax (16 lanes per row, barrier-free) + p write ----
    {
        float mx = -INFINITY;
        #pragma unroll
        for (int s = 0; s < 16; ++s) mx = fmaxf(mx, sc[i][jj + 16*s]);
        #pragma unroll
        for (int off = 8; off >= 1; off >>= 1) mx = fmaxf(mx, __shfl_xor(mx, off, 16));

        float sum = 0.f;
        float ev[16];
        #pragma unroll
        for (int s = 0; s < 16; ++s) {
            ev[s] = __expf(sc[i][jj + 16*s] - mx);
            sum += ev[s];
        }
        #pragma unroll
        for (int off = 8; off >= 1; off >>= 1) sum += __shfl_xor(sum, off, 16);
        float inv = 1.0f / sum;

        u16* prow = Pout + ((size_t)bh * NL + l0 + i) * NL;
        #pragma unroll
        for (int s = 0; s < 16; ++s)
            prow[jj + 16*s] = f2bf(ev[s] * inv);
    }
}

// ---------------------------------------------------------------------------
// Kernel E: ctx.  ctx[b,h,l,d] = sum_m p * (v + rel_v).   (round-12 exact)
// One block per (b,l), natural bl mapping; streams the 512 KB rel_v slice
// (nontemporal); p staged from bf16; V read bf16; pw stride-260 pad.
// ---------------------------------------------------------------------------
__global__ __launch_bounds__(256)
void ctx_kernel(const u16* __restrict__ P, const u16* __restrict__ V,
                const float* __restrict__ RV, u16* __restrict__ CTXB)
{
    const int bl = blockIdx.x;
    const int b  = bl >> 8;
    const int l  = bl & 255;
    const int t  = threadIdx.x;

    __shared__ float pw[8][260];   // padded: bank(hc*260+m) distinct per hc
    __shared__ f32x4 redv[128];

    #pragma unroll
    for (int rep = 0; rep < 2; ++rep) {
        int e = t + rep * 256;     // 0..511; u16x4 (8B) each
        int h = e >> 6, c = (e & 63) * 4;
        u16x4 pv = *(const u16x4*)&P[(((size_t)(b*NH + h) * NL) + l) * NL + c];
        pw[h][c+0] = bf2f(pv.x); pw[h][c+1] = bf2f(pv.y);
        pw[h][c+2] = bf2f(pv.z); pw[h][c+3] = bf2f(pv.w);
    }
    __syncthreads();

    const int c    = t & 127;    // float4-column 0..127 (head = c>>4)
    const int half = t >> 7;     // m parity
    const int hc   = c >> 4;
    const int dk4  = c & 15;

    const f32x4* rv4 = (const f32x4*)RV + (size_t)bl * NL * 128 + c;
    const u16*   vvp = V + ((size_t)(b*NH + hc) * NL) * 64 + dk4 * 4;

    f32x4 acc = {0.f, 0.f, 0.f, 0.f};
    #pragma unroll 4
    for (int m = half; m < NL; m += 2) {
        float  w  = pw[hc][m];
        f32x4 rv = __builtin_nontemporal_load(rv4 + (size_t)m * 128);
        u16x4 vw = *(const u16x4*)(vvp + (size_t)m * 64);
        acc.x += w * (rv.x + bf2f(vw.x));
        acc.y += w * (rv.y + bf2f(vw.y));
        acc.z += w * (rv.z + bf2f(vw.z));
        acc.w += w * (rv.w + bf2f(vw.w));
    }

    if (half) redv[c] = acc;
    __syncthreads();
    if (!half) {
        f32x4 r2 = redv[c];
        acc.x += r2.x; acc.y += r2.y; acc.z += r2.z; acc.w += r2.w;
        u16x4 o;
        o.x = f2bf(acc.x); o.y = f2bf(acc.y); o.z = f2bf(acc.z); o.w = f2bf(acc.w);
        *(u16x4*)&CTXB[(size_t)bl * ND + c*4] = o;
    }
}

// ---------------------------------------------------------------------------
// Kernel F: out = ctx @ Wo^T + bo via MFMA.  32x64 tiles, grid (32,8)=256.
// wave w: rows (w&1)*16, cols (w>>1)*32.   (round-12 exact)
// ---------------------------------------------------------------------------
__global__ __launch_bounds__(256)
void out_proj_mfma_kernel(const u16* __restrict__ A, const u16* __restrict__ W,
                          const float* __restrict__ bias, float* __restrict__ C)
{
    const int t    = threadIdx.x;
    const int wv_  = t >> 6;
    const int lane = t & 63;
    const int lr   = lane & 15;
    const int kg   = lane >> 4;

    const int m0 = blockIdx.x * 32 + (wv_ & 1) * 16;
    const int n0 = blockIdx.y * 64 + (wv_ >> 1) * 32;

    const u16* Ap = A + (size_t)(m0 + lr) * ND + kg * 8;
    const u16* Bp = W + (size_t)(n0 + lr) * ND + kg * 8;

    f32x4 acc[2] = {{0,0,0,0},{0,0,0,0}};

    for (int kt = 0; kt < 16; ++kt) {
        s16x8 a = *(const s16x8*)(Ap + kt * 32);
        #pragma unroll
        for (int nt = 0; nt < 2; ++nt) {
            s16x8 b = *(const s16x8*)(Bp + (size_t)nt * 16 * ND + kt * 32);
            acc[nt] = __builtin_amdgcn_mfma_f32_16x16x32_bf16(a, b, acc[nt], 0, 0, 0);
        }
    }

    #pragma unroll
    for (int nt = 0; nt < 2; ++nt) {
        const int col = n0 + nt * 16 + lr;
        const float bb = bias[col];
        #pragma unroll
        for (int r = 0; r < 4; ++r) {
            int row = m0 + kg * 4 + r;
            C[(size_t)row * ND + col] = acc[nt][r] + bb;
        }
    }
}

// ---------------------------------------------------------------------------
extern "C" void kernel_launch(void* const* d_in, const int* in_sizes, int n_in,
                              void* d_out, int out_size, void* d_ws, size_t ws_size,
                              hipStream_t stream)
{
    const float* query   = (const float*)d_in[0];
    const float* key     = (const float*)d_in[1];
    const float* value   = (const float*)d_in[2];
    const void*  mask    = d_in[3];
    const int*   rel_pos = (const int*)d_in[4];
    const float* rel_q   = (const float*)d_in[5];
    const float* rel_k   = (const float*)d_in[6];
    const float* rel_v   = (const float*)d_in[7];
    const float* Wq = (const float*)d_in[8];
    const float* bq = (const float*)d_in[9];
    const float* Wk = (const float*)d_in[10];
    const float* bk = (const float*)d_in[11];
    const float* Wv = (const float*)d_in[12];
    const float* bv = (const float*)d_in[13];
    const float* Wo = (const float*)d_in[14];
    const float* bo = (const float*)d_in[15];

    // ---- workspace layout ----
    float* wsf  = (float*)d_ws;
    float* c2p  = wsf;                    // 524288 f32
    float* b3   = c2p + 524288;           // 512 f32
    float* b2   = b3 + 512;               // 512 f32
    u16* wsu  = (u16*)(b2 + 512);
    u16* xqb  = wsu;                      // 524288 u16
    u16* xkb  = xqb + 524288;
    u16* xvb  = xkb + 524288;
    u16* wqb  = xvb + 524288;             // 262144 u16
    u16* wkb  = wqb + 262144;
    u16* wvb  = wkb + 262144;
    u16* wob  = wvb + 262144;
    u16* w3b  = wob + 262144;
    u16* w2b  = w3b + 262144;
    u16* qbf  = w2b + 262144;             // 524288 u16
    u16* kbf  = qbf + 524288;
    u16* vbf  = kbf + 524288;             // 524288 u16 (bf16 V)
    u16* p2cb = vbf + 524288;             // 524288 u16 [B,H,M,64]
    u16* pb   = p2cb + 524288;            // 2097152 u16 [B,H,L,M] (bf16 p)
    u16* ctxb = pb + 2097152;             // 524288 u16

    prep_kernel<<<dim3(512, 10), 256, 0, stream>>>(
        query, key, value, Wq, bq, Wk, bk, Wv, Wo, rel_k, rel_q,
        xqb, xkb, xvb, wqb, wkb, wvb, wob, w3b, b3, w2b, b2);

    gemm5_mfma_kernel<<<dim3(16, 8, 5), 256, 0, stream>>>(
        xqb, xkb, xvb, wqb, wkb, wvb, w3b, w2b,
        bq, bk, bv, b3, b2, qbf, kbf, vbf, c2p, p2cb);

    scores_kernel<<<dim3(16, 32), 256, 0, stream>>>(
        qbf, kbf, c2p, p2cb, rel_pos, mask, pb);

    ctx_kernel<<<dim3(1024), 256, 0, stream>>>(pb, vbf, rel_v, ctxb);

    out_proj_mfma_kernel<<<dim3(32, 8), 256, 0, stream>>>(ctxb, wob, bo, (float*)d_out);
}

// Round 14
// 141.653 us; speedup vs baseline: 1.1473x; 1.0151x over previous
//
#include <hip/hip_runtime.h>
#include <hip/hip_bf16.h>
#include <math.h>

#define NB 4
#define NL 256
#define ND 512
#define NH 8
#define NR 64
#define NDK 64

typedef float f32x4 __attribute__((ext_vector_type(4)));
typedef short s16x8 __attribute__((ext_vector_type(8)));
typedef unsigned short u16;
typedef u16 u16x4 __attribute__((ext_vector_type(4)));
typedef u16 u16x8 __attribute__((ext_vector_type(8)));
typedef unsigned int u32;

static __device__ __forceinline__ u16 f2bf(float f) {
    __hip_bfloat16 h = __float2bfloat16(f);   // RNE
    return __builtin_bit_cast(unsigned short, h);
}
static __device__ __forceinline__ float bf2f(u16 u) {
    return __builtin_bit_cast(float, (u32)u << 16);
}

// ---------------------------------------------------------------------------
// Kernel A (MERGED convert + wprep): blockIdx.y = job.   (round-13 exact)
//  jobs 0-2: convert query/key/value f32->bf16 (524288 elems, 512 blocks)
//  jobs 3-6: convert Wq/Wk/Wv/Wo f32->bf16 (262144 elems, 256 blocks used)
//  jobs 7-8: W3 = rel_k x Wq_head / W2 = rel_q x Wk_head (bf16 out, 64 blocks)
//  job  9  : b3/b2 bias dots (2 blocks)
// ---------------------------------------------------------------------------
__global__ __launch_bounds__(256)
void prep_kernel(const float* __restrict__ q, const float* __restrict__ k,
                 const float* __restrict__ v,
                 const float* __restrict__ Wq, const float* __restrict__ bq,
                 const float* __restrict__ Wk, const float* __restrict__ bk,
                 const float* __restrict__ Wv, const float* __restrict__ Wo,
                 const float* __restrict__ RelK, const float* __restrict__ RelQ,
                 u16* __restrict__ oq, u16* __restrict__ ok, u16* __restrict__ ov,
                 u16* __restrict__ owq, u16* __restrict__ owk,
                 u16* __restrict__ owv, u16* __restrict__ owo,
                 u16* __restrict__ W3, float* __restrict__ b3,
                 u16* __restrict__ W2, float* __restrict__ b2)
{
    const int job = blockIdx.y;
    const int t   = threadIdx.x;

    __shared__ float At[64][68];   // wprep branch only
    __shared__ float Bs[64][68];

    if (job < 7) {
        const float* src; u16* dst; int n;
        switch (job) {
            case 0: src = q;  dst = oq;  n = 524288; break;
            case 1: src = k;  dst = ok;  n = 524288; break;
            case 2: src = v;  dst = ov;  n = 524288; break;
            case 3: src = Wq; dst = owq; n = 262144; break;
            case 4: src = Wk; dst = owk; n = 262144; break;
            case 5: src = Wv; dst = owv; n = 262144; break;
            default: src = Wo; dst = owo; n = 262144; break;
        }
        int idx = (blockIdx.x * 256 + t) * 4;
        if (idx >= n) return;
        f32x4 x = *(const f32x4*)&src[idx];
        u16x4 o;
        o.x = f2bf(x.x); o.y = f2bf(x.y); o.z = f2bf(x.z); o.w = f2bf(x.w);
        *(u16x4*)&dst[idx] = o;
        return;
    }

    if (job == 9) {
        if (blockIdx.x >= 2) return;
        const float* rel  = blockIdx.x ? RelQ : RelK;
        const float* bias = blockIdx.x ? bk : bq;
        float* out        = blockIdx.x ? b2 : b3;
        for (int hr = t; hr < 512; hr += 256) {
            int h = hr >> 6, r = hr & 63;
            float s = 0.f;
            #pragma unroll 8
            for (int d = 0; d < 64; ++d)
                s += rel[((size_t)h * NR + r) * NDK + d] * bias[h * 64 + d];
            out[hr] = s;
        }
        return;
    }

    // jobs 7,8: W3/W2 GEMM (64 blocks each)
    if (blockIdx.x >= 64) return;
    const int z = job - 7;                 // 0: W3 (rel_k,Wq), 1: W2 (rel_q,Wk)
    const float* rel = z ? RelQ : RelK;    // [8][64][64]
    const float* W   = z ? Wk : Wq;        // [512][512]
    u16* Wout        = z ? W2 : W3;

    const int h  = blockIdx.x >> 3;
    const int e0 = (blockIdx.x & 7) * 64;

    const int ty = t >> 4, tx = t & 15;

    #pragma unroll
    for (int pass = 0; pass < 4; ++pass) {
        {
            int lr = t >> 2, lk = (t & 3) << 2;
            f32x4 a = *(const f32x4*)&rel[((size_t)h * NR + lr) * NDK + pass * 16 + lk];
            At[pass*16 + lk + 0][lr] = a.x; At[pass*16 + lk + 1][lr] = a.y;
            At[pass*16 + lk + 2][lr] = a.z; At[pass*16 + lk + 3][lr] = a.w;
        }
        {
            int dr = t >> 4, ec = (t & 15) << 2;
            *(f32x4*)&Bs[pass*16 + dr][ec] =
                *(const f32x4*)&W[(size_t)(h*64 + pass*16 + dr) * ND + e0 + ec];
        }
    }
    __syncthreads();

    float acc[4][4] = {{0.f,0.f,0.f,0.f},{0.f,0.f,0.f,0.f},
                       {0.f,0.f,0.f,0.f},{0.f,0.f,0.f,0.f}};
    #pragma unroll 16
    for (int kk = 0; kk < 64; ++kk) {
        f32x4 a4 = *(const f32x4*)&At[kk][ty*4];
        f32x4 b4 = *(const f32x4*)&Bs[kk][tx*4];
        #pragma unroll
        for (int i = 0; i < 4; ++i) {
            acc[i][0] += a4[i]*b4.x; acc[i][1] += a4[i]*b4.y;
            acc[i][2] += a4[i]*b4.z; acc[i][3] += a4[i]*b4.w;
        }
    }

    #pragma unroll
    for (int i = 0; i < 4; ++i) {
        u16x4 o;
        o.x = f2bf(acc[i][0]); o.y = f2bf(acc[i][1]);
        o.z = f2bf(acc[i][2]); o.w = f2bf(acc[i][3]);
        *(u16x4*)&Wout[(size_t)(h*64 + ty*4 + i) * ND + e0 + tx*4] = o;
    }
}

// ---------------------------------------------------------------------------
// Kernel C: batched projection via MFMA (no LDS).   (round-13 exact)
//  z=0 q->bf16, z=1 k->bf16, z=2 v->bf16, z=3 c2p->f32, z=4 p2c->bf16.
// Block = 64 rows x 64 cols (one head); 4 waves.
// D layout (m89-verified): row=(lane>>4)*4+reg, col=lane&15.
// ---------------------------------------------------------------------------
__global__ __launch_bounds__(256)
void gemm5_mfma_kernel(const u16* __restrict__ xq, const u16* __restrict__ xk,
                       const u16* __restrict__ xv,
                       const u16* __restrict__ wq, const u16* __restrict__ wk,
                       const u16* __restrict__ wv, const u16* __restrict__ w3,
                       const u16* __restrict__ w2,
                       const float* __restrict__ bq, const float* __restrict__ bk,
                       const float* __restrict__ bv, const float* __restrict__ b3,
                       const float* __restrict__ b2,
                       u16* __restrict__ qbf, u16* __restrict__ kbf,
                       u16* __restrict__ vbf, float* __restrict__ c2p,
                       u16* __restrict__ p2cb)
{
    const int z = blockIdx.z;
    const u16* __restrict__ X = (z==0 || z==3) ? xq : ((z==1 || z==4) ? xk : xv);
    const u16* __restrict__ W = (z==0)?wq:(z==1)?wk:(z==2)?wv:(z==3)?w3:w2;
    const float* __restrict__ bias = (z==0)?bq:(z==1)?bk:(z==2)?bv:(z==3)?b3:b2;

    const int t    = threadIdx.x;
    const int wv_  = t >> 6;
    const int lane = t & 63;
    const int lr   = lane & 15;
    const int kg   = lane >> 4;

    const int m0 = blockIdx.x * 64 + wv_ * 16;
    const int h  = blockIdx.y;
    const int n0 = h * 64;

    const u16* Ap = X + (size_t)(m0 + lr) * ND + kg * 8;
    const u16* Bp = W + (size_t)(n0 + lr) * ND + kg * 8;

    f32x4 acc[4] = {{0,0,0,0},{0,0,0,0},{0,0,0,0},{0,0,0,0}};

    for (int kt = 0; kt < 16; ++kt) {
        s16x8 a = *(const s16x8*)(Ap + kt * 32);
        #pragma unroll
        for (int nt = 0; nt < 4; ++nt) {
            s16x8 b = *(const s16x8*)(Bp + (size_t)nt * 16 * ND + kt * 32);
            acc[nt] = __builtin_amdgcn_mfma_f32_16x16x32_bf16(a, b, acc[nt], 0, 0, 0);
        }
    }

    #pragma unroll
    for (int nt = 0; nt < 4; ++nt) {
        const int col = n0 + nt * 16 + lr;
        const float bb = bias[col];
        #pragma unroll
        for (int r = 0; r < 4; ++r) {
            int row = m0 + kg * 4 + r;
            int bI  = row >> 8;
            int lI  = row & 255;
            size_t oidx = (((size_t)(bI * NH + h)) * NL + lI) * 64 + nt * 16 + lr;
            float val = acc[nt][r] + bb;
            if      (z == 0) qbf[oidx]  = f2bf(val);
            else if (z == 1) kbf[oidx]  = f2bf(val);
            else if (z == 2) vbf[oidx]  = f2bf(val);
            else if (z == 3) c2p[oidx]  = val;
            else             p2cb[oidx] = f2bf(val);
        }
    }
}

// ---------------------------------------------------------------------------
// Kernel D: scores + gathers + softmax -> p bf16 [B,H,L,M]  (round-13 exact)
// Block = (16 l-rows, bh), 256 thr (4 waves), grid (16,32)=512.
// ---------------------------------------------------------------------------
__global__ __launch_bounds__(256)
void scores_kernel(const u16* __restrict__ qbf, const u16* __restrict__ kbf,
                   const float* __restrict__ C2P, const u16* __restrict__ P2Cb,
                   const int* __restrict__ RelPos, const void* __restrict__ MaskP,
                   u16* __restrict__ Pout)
{
    const int bh = blockIdx.y;
    const int b  = bh >> 3;
    const int l0 = blockIdx.x * 16;
    const int t  = threadIdx.x;

    __shared__ float sc[16][257];     // scores -> p   (16.4 KB)
    __shared__ u16   psall[256][68];  // p2c bf16      (34.8 KB, padded)
    __shared__ float cs[16][68];      // c2p           (4.3 KB, padded)
    __shared__ float maskv[256];      // mask row      (1 KB)

    // ---- detect mask buffer layout (bool-u8 / f32 / i32), deterministic ----
    const unsigned char* mu = (const unsigned char*)MaskP;
    int loc1  = mu[t*4 + 1];
    int loc23 = mu[t*4 + 2] | mu[t*4 + 3];
    int any1  = __syncthreads_or(loc1);
    int any23 = __syncthreads_or(loc23);
    const int mlayout = any1 ? 0 : (any23 ? 1 : 2);  // 0=u8, 1=f32, 2=i32

    {
        float mval;
        if (mlayout == 0)      mval = (float)mu[b * NL + t];
        else if (mlayout == 1) mval = ((const float*)MaskP)[b * NL + t];
        else                   mval = (float)((const int*)MaskP)[b * NL + t];
        maskv[t] = mval;
        // c2p rows of this l-tile: row = t>>4, f32x4 col (t&15)*4
        *(f32x4*)&cs[t >> 4][(t & 15) * 4] =
            *(const f32x4*)&C2P[(((size_t)bh * NL) + l0 + (t >> 4)) * NR + (t & 15) * 4];
    }

    // ---- stage p2c[b,h]: 256x64 bf16, 2048 x 16B coalesced reads ----
    #pragma unroll
    for (int rep = 0; rep < 8; ++rep) {
        int e = t + rep * 256;           // 0..2047
        *(u16x8*)&psall[e >> 3][(e & 7) * 8] =
            *(const u16x8*)&P2Cb[((size_t)bh * NL + (e >> 3)) * 64 + (e & 7) * 8];
    }

    // ---- QK^T MFMA: wave w owns m-stripe w*64 (four 16-col tiles) ----
    {
        const int wv_  = t >> 6;
        const int lane = t & 63;
        const int lr   = lane & 15;
        const int kg   = lane >> 4;
        const u16* Ap = qbf + ((size_t)bh * NL + l0 + lr) * 64 + kg * 8;
        s16x8 a0 = *(const s16x8*)Ap;
        s16x8 a1 = *(const s16x8*)(Ap + 32);
        #pragma unroll
        for (int c = 0; c < 4; ++c) {
            int m0 = wv_ * 64 + c * 16;
            const u16* Bp = kbf + ((size_t)bh * NL + m0 + lr) * 64 + kg * 8;
            s16x8 b0 = *(const s16x8*)Bp;
            s16x8 b1 = *(const s16x8*)(Bp + 32);
            f32x4 acc = {0.f, 0.f, 0.f, 0.f};
            acc = __builtin_amdgcn_mfma_f32_16x16x32_bf16(a0, b0, acc, 0, 0, 0);
            acc = __builtin_amdgcn_mfma_f32_16x16x32_bf16(a1, b1, acc, 0, 0, 0);
            #pragma unroll
            for (int r = 0; r < 4; ++r)
                sc[kg * 4 + r][m0 + lr] = acc[r];
        }
    }
    __syncthreads();

    // ---- Phase B: gather + scale + mask (barrier-free) ----
    const int i  = t >> 4;        // row 0..15
    const int jj = t & 15;        // lane 0..15
    {
        const size_t rowbase = ((size_t)b * NL + l0 + i) * NL;
        #pragma unroll
        for (int s = 0; s < 16; ++s) {
            const int m = s * 16 + jj;
            int r = RelPos[rowbase + m];
            float val = sc[i][m] + cs[i][r] + bf2f(psall[m][r]);
            val *= (1.0f / 24.0f);   // 1 / (3 * sqrt(64))
            if (maskv[m] != 0.0f) val = -1e9f;
            sc[i][m] = val;          // same thread re-reads below
        }
    }

    // ---- Phase C: softmax (16 lanes per row, barrier-free) + p write ----
    {
        float mx = -INFINITY;
        #pragma unroll
        for (int s = 0; s < 16; ++s) mx = fmaxf(mx, sc[i][jj + 16*s]);
        #pragma unroll
        for (int off = 8; off >= 1; off >>= 1) mx = fmaxf(mx, __shfl_xor(mx, off, 16));

        float sum = 0.f;
        float ev[16];
        #pragma unroll
        for (int s = 0; s < 16; ++s) {
            ev[s] = __expf(sc[i][jj + 16*s] - mx);
            sum += ev[s];
        }
        #pragma unroll
        for (int off = 8; off >= 1; off >>= 1) sum += __shfl_xor(sum, off, 16);
        float inv = 1.0f / sum;

        u16* prow = Pout + ((size_t)bh * NL + l0 + i) * NL;
        #pragma unroll
        for (int s = 0; s < 16; ++s)
            prow[jj + 16*s] = f2bf(ev[s] * inv);
    }
}

// ---------------------------------------------------------------------------
// Kernel E: ctx.  ctx[b,h,l,d] = sum_m p * (v + rel_v).
// CHANGE vs round 13 (the ONE variable): split each (b,l) by d-half ->
// grid 2048 = 8 blocks/CU = 32 waves/CU (was 4/16).  Block handles 64
// f32x4-columns (4 heads) with a 4-way m-parity split (64 m-steps/thread).
// rel_v reads per wave: contiguous 1 KB chunk per m-row (stride 2 KB).
// ---------------------------------------------------------------------------
__global__ __launch_bounds__(256)
void ctx_kernel(const u16* __restrict__ P, const u16* __restrict__ V,
                const float* __restrict__ RV, u16* __restrict__ CTXB)
{
    const int bid = blockIdx.x;          // 0..2047
    const int bl  = bid >> 1;            // (b,l)
    const int dh  = bid & 1;             // d-half (f32x4 cols dh*64..+63)
    const int b   = bl >> 8;
    const int t   = threadIdx.x;

    __shared__ float pw[4][260];   // 4 heads' p rows (padded stride)
    __shared__ f32x4 redv[3][64];  // cross-parity reduce

    // stage p rows for heads dh*4 .. dh*4+3 (1024 bf16, 8B per thread)
    {
        int hl = t >> 6;               // 0..3
        int c4 = (t & 63) * 4;
        int l  = bl & 255;
        u16x4 pv = *(const u16x4*)&P[(((size_t)(b*NH + dh*4 + hl) * NL) + l) * NL + c4];
        pw[hl][c4+0] = bf2f(pv.x); pw[hl][c4+1] = bf2f(pv.y);
        pw[hl][c4+2] = bf2f(pv.z); pw[hl][c4+3] = bf2f(pv.w);
    }
    __syncthreads();

    const int cl  = t & 63;        // f32x4 column within half, 0..63
    const int par = t >> 6;        // m parity 0..3
    const int hl  = cl >> 4;       // head within half, 0..3
    const int dk4 = cl & 15;

    const f32x4* rv4 = (const f32x4*)RV + (size_t)bl * NL * 128 + dh * 64 + cl;
    const u16*   vvp = V + ((size_t)(b*NH + dh*4 + hl) * NL) * 64 + dk4 * 4;

    f32x4 acc = {0.f, 0.f, 0.f, 0.f};
    #pragma unroll 4
    for (int m = par; m < NL; m += 4) {
        float  w  = pw[hl][m];
        f32x4 rv = __builtin_nontemporal_load(rv4 + (size_t)m * 128);
        u16x4 vw = *(const u16x4*)(vvp + (size_t)m * 64);
        acc.x += w * (rv.x + bf2f(vw.x));
        acc.y += w * (rv.y + bf2f(vw.y));
        acc.z += w * (rv.z + bf2f(vw.z));
        acc.w += w * (rv.w + bf2f(vw.w));
    }

    if (par) redv[par-1][cl] = acc;
    __syncthreads();
    if (par == 0) {
        f32x4 r0 = redv[0][cl], r1 = redv[1][cl], r2 = redv[2][cl];
        acc.x += r0.x + r1.x + r2.x;
        acc.y += r0.y + r1.y + r2.y;
        acc.z += r0.z + r1.z + r2.z;
        acc.w += r0.w + r1.w + r2.w;
        u16x4 o;
        o.x = f2bf(acc.x); o.y = f2bf(acc.y); o.z = f2bf(acc.z); o.w = f2bf(acc.w);
        *(u16x4*)&CTXB[(size_t)bl * ND + dh * 256 + cl * 4] = o;
    }
}

// ---------------------------------------------------------------------------
// Kernel F: out = ctx @ Wo^T + bo via MFMA.  32x64 tiles, grid (32,8)=256.
// wave w: rows (w&1)*16, cols (w>>1)*32.   (round-13 exact)
// ---------------------------------------------------------------------------
__global__ __launch_bounds__(256)
void out_proj_mfma_kernel(const u16* __restrict__ A, const u16* __restrict__ W,
                          const float* __restrict__ bias, float* __restrict__ C)
{
    const int t    = threadIdx.x;
    const int wv_  = t >> 6;
    const int lane = t & 63;
    const int lr   = lane & 15;
    const int kg   = lane >> 4;

    const int m0 = blockIdx.x * 32 + (wv_ & 1) * 16;
    const int n0 = blockIdx.y * 64 + (wv_ >> 1) * 32;

    const u16* Ap = A + (size_t)(m0 + lr) * ND + kg * 8;
    const u16* Bp = W + (size_t)(n0 + lr) * ND + kg * 8;

    f32x4 acc[2] = {{0,0,0,0},{0,0,0,0}};

    for (int kt = 0; kt < 16; ++kt) {
        s16x8 a = *(const s16x8*)(Ap + kt * 32);
        #pragma unroll
        for (int nt = 0; nt < 2; ++nt) {
            s16x8 b = *(const s16x8*)(Bp + (size_t)nt * 16 * ND + kt * 32);
            acc[nt] = __builtin_amdgcn_mfma_f32_16x16x32_bf16(a, b, acc[nt], 0, 0, 0);
        }
    }

    #pragma unroll
    for (int nt = 0; nt < 2; ++nt) {
        const int col = n0 + nt * 16 + lr;
        const float bb = bias[col];
        #pragma unroll
        for (int r = 0; r < 4; ++r) {
            int row = m0 + kg * 4 + r;
            C[(size_t)row * ND + col] = acc[nt][r] + bb;
        }
    }
}

// ---------------------------------------------------------------------------
extern "C" void kernel_launch(void* const* d_in, const int* in_sizes, int n_in,
                              void* d_out, int out_size, void* d_ws, size_t ws_size,
                              hipStream_t stream)
{
    const float* query   = (const float*)d_in[0];
    const float* key     = (const float*)d_in[1];
    const float* value   = (const float*)d_in[2];
    const void*  mask    = d_in[3];
    const int*   rel_pos = (const int*)d_in[4];
    const float* rel_q   = (const float*)d_in[5];
    const float* rel_k   = (const float*)d_in[6];
    const float* rel_v   = (const float*)d_in[7];
    const float* Wq = (const float*)d_in[8];
    const float* bq = (const float*)d_in[9];
    const float* Wk = (const float*)d_in[10];
    const float* bk = (const float*)d_in[11];
    const float* Wv = (const float*)d_in[12];
    const float* bv = (const float*)d_in[13];
    const float* Wo = (const float*)d_in[14];
    const float* bo = (const float*)d_in[15];

    // ---- workspace layout ----
    float* wsf  = (float*)d_ws;
    float* c2p  = wsf;                    // 524288 f32
    float* b3   = c2p + 524288;           // 512 f32
    float* b2   = b3 + 512;               // 512 f32
    u16* wsu  = (u16*)(b2 + 512);
    u16* xqb  = wsu;                      // 524288 u16
    u16* xkb  = xqb + 524288;
    u16* xvb  = xkb + 524288;
    u16* wqb  = xvb + 524288;             // 262144 u16
    u16* wkb  = wqb + 262144;
    u16* wvb  = wkb + 262144;
    u16* wob  = wvb + 262144;
    u16* w3b  = wob + 262144;
    u16* w2b  = w3b + 262144;
    u16* qbf  = w2b + 262144;             // 524288 u16
    u16* kbf  = qbf + 524288;
    u16* vbf  = kbf + 524288;             // 524288 u16 (bf16 V)
    u16* p2cb = vbf + 524288;             // 524288 u16 [B,H,M,64]
    u16* pb   = p2cb + 524288;            // 2097152 u16 [B,H,L,M] (bf16 p)
    u16* ctxb = pb + 2097152;             // 524288 u16

    prep_kernel<<<dim3(512, 10), 256, 0, stream>>>(
        query, key, value, Wq, bq, Wk, bk, Wv, Wo, rel_k, rel_q,
        xqb, xkb, xvb, wqb, wkb, wvb, wob, w3b, b3, w2b, b2);

    gemm5_mfma_kernel<<<dim3(16, 8, 5), 256, 0, stream>>>(
        xqb, xkb, xvb, wqb, wkb, wvb, w3b, w2b,
        bq, bk, bv, b3, b2, qbf, kbf, vbf, c2p, p2cb);

    scores_kernel<<<dim3(16, 32), 256, 0, stream>>>(
        qbf, kbf, c2p, p2cb, rel_pos, mask, pb);

    ctx_kernel<<<dim3(2048), 256, 0, stream>>>(pb, vbf, rel_v, ctxb);

    out_proj_mfma_kernel<<<dim3(32, 8), 256, 0, stream>>>(ctxb, wob, bo, (float*)d_out);
}